// Round 2
// baseline (547.939 us; speedup 1.0000x reference)
//
#include <hip/hip_runtime.h>
#include <math.h>

#define N_NODES 100000
#define N_EDGES 3200000
#define F_IN    37
#define H_DIM   16
#define C_DIM   2

#define BUCKET_BITS 7
#define BUCKET_SZ   128
#define NXW1        782          // ceil(100000/128) xw1 blocks
#define NSCAN       98           // ceil(100000/1024) scan blocks

// count in bits [42,63], wsum fixed-point 2^-32 in bits [0,41]
#define CNT_SHIFT 42
#define WSUM_MASK ((1ull << CNT_SHIFT) - 1)

__device__ __forceinline__ unsigned bf16rne(float f) {
    unsigned u = __float_as_uint(f);
    return (u + 0x7FFFu + ((u >> 16) & 1u)) >> 16;
}
#define BLO(u) __uint_as_float((u) << 16)
#define BHI(u) __uint_as_float((u) & 0xFFFF0000u)
// compact edge decode: u = (w_bf16 << 17) | row   (w in [0,1) => sign bit 0)
#define EW(u)  __uint_as_float(((u) >> 17) << 16)
#define ER(u)  ((u) & 0x1FFFFu)

// ---------- pass 1: per-node edge count + exact weight sum in ONE u64 atomic.
// Replaces the entire two-level LDS counting sort's histogram role.
__global__ __launch_bounds__(256) void k_hist(
    const int* __restrict__ col, const float* __restrict__ w,
    unsigned long long* __restrict__ acc)
{
    int i = blockIdx.x * 256 + threadIdx.x;       // edge-quad index, exact fit
    const int4   c4 = ((const int4*)col)[i];
    const float4 w4 = ((const float4*)w)[i];
    // w in [0,1): w*2^32 < 2^32, exact float scaling (pow2), truncation < 2^-32
    atomicAdd(&acc[c4.x], (1ull << CNT_SHIFT) | (unsigned long long)(w4.x * 4294967296.0f));
    atomicAdd(&acc[c4.y], (1ull << CNT_SHIFT) | (unsigned long long)(w4.y * 4294967296.0f));
    atomicAdd(&acc[c4.z], (1ull << CNT_SHIFT) | (unsigned long long)(w4.z * 4294967296.0f));
    atomicAdd(&acc[c4.w], (1ull << CNT_SHIFT) | (unsigned long long)(w4.w * 4294967296.0f));
}

// ---------- scan stage A: per-1024-node block exclusive scan + block totals ----------
__global__ __launch_bounds__(1024) void k_scan1(
    const unsigned long long* __restrict__ acc,
    int* __restrict__ tmpbase, int* __restrict__ partial)
{
    __shared__ int wscan[16];
    int t = threadIdx.x, n = blockIdx.x * 1024 + t;
    int c = (n < N_NODES) ? (int)(acc[n] >> CNT_SHIFT) : 0;
    int lane = t & 63, wid = t >> 6;
    int v = c;
#pragma unroll
    for (int d = 1; d < 64; d <<= 1) {
        int u = __shfl_up(v, d);
        if (lane >= d) v += u;
    }
    if (lane == 63) wscan[wid] = v;
    __syncthreads();
    if (wid == 0) {
        int u = (lane < 16) ? wscan[lane] : 0;
#pragma unroll
        for (int d = 1; d < 16; d <<= 1) {
            int u2 = __shfl_up(u, d);
            if (lane >= d) u += u2;
        }
        if (lane < 16) wscan[lane] = u;
    }
    __syncthreads();
    int incl = v + ((wid > 0) ? wscan[wid - 1] : 0);
    tmpbase[n] = incl - c;                        // exclusive within block
    if (t == 1023) partial[blockIdx.x] = incl;    // block total
}

// ---------- scan stage B: exclusive scan of the 98 block totals ----------
__global__ __launch_bounds__(128) void k_scan2(
    const int* __restrict__ partial, int* __restrict__ blockoff)
{
    __shared__ int ws2[2];
    int t = threadIdx.x;
    int c = (t < NSCAN) ? partial[t] : 0;
    int lane = t & 63, wid = t >> 6;
    int v = c;
#pragma unroll
    for (int d = 1; d < 64; d <<= 1) {
        int u = __shfl_up(v, d);
        if (lane >= d) v += u;
    }
    if (lane == 63) ws2[wid] = v;
    __syncthreads();
    int incl = v + ((wid > 0) ? ws2[0] : 0);
    if (t < NSCAN) blockoff[t] = incl - c;        // exclusive across blocks
}

// ---------- fused: CSR meta (rp, cur) + dinv + h1b = bf16(dinv * (x @ W1)) ----------
__global__ __launch_bounds__(1024) void k_xw1(
    const unsigned long long* __restrict__ acc,
    const int* __restrict__ tmpbase, const int* __restrict__ blockoff,
    const float* __restrict__ x, const float* __restrict__ W1,
    int2* __restrict__ rp, int* __restrict__ cur,
    float* __restrict__ dinv, unsigned* __restrict__ h1b)
{
    __shared__ float xs[BUCKET_SZ * F_IN];        // 18.5 KB
    __shared__ float sW[F_IN * H_DIM];            // 2.4 KB
    __shared__ float sdinv[BUCKET_SZ];
    int t = threadIdx.x, b = blockIdx.x;
    int nbase = b << BUCKET_BITS;

    // per-node meta: dinv, CSR base, cursor init
    if (t < BUCKET_SZ) {
        int c = nbase + t;
        if (c < N_NODES) {
            unsigned long long a = acc[c];
            int cn = (int)(a >> CNT_SHIFT);
            float wsum = (float)(a & WSUM_MASK) * 2.3283064365386963e-10f; // 2^-32
            float di = rsqrtf(wsum + 1.0f);       // + self-loop
            sdinv[t] = di;
            int base = tmpbase[c] + blockoff[c >> 10];
            rp[c] = make_int2(base, cn);
            cur[c] = base;
            dinv[c] = di;
        }
    }
    for (int idx = t; idx < F_IN * H_DIM; idx += 1024) sW[idx] = W1[idx];
    {
        const float4* x4 = (const float4*)(x + (size_t)nbase * F_IN);
        const int nv4 = (BUCKET_SZ * F_IN) / 4;   // 1184
        int gf0 = nbase * F_IN;
        for (int idx = t; idx < nv4; idx += 1024) {
            int gf = gf0 + 4 * idx;
            float4 v;
            if (gf + 3 < N_NODES * F_IN) {
                v = x4[idx];
            } else {
                v.x = (gf + 0 < N_NODES * F_IN) ? x[gf + 0] : 0.f;
                v.y = (gf + 1 < N_NODES * F_IN) ? x[gf + 1] : 0.f;
                v.z = (gf + 2 < N_NODES * F_IN) ? x[gf + 2] : 0.f;
                v.w = (gf + 3 < N_NODES * F_IN) ? x[gf + 3] : 0.f;
            }
            ((float4*)xs)[idx] = v;
        }
    }
    __syncthreads();
    // 8 threads/node, each computes 2 output cols {2*sub, 2*sub+1}
    {
        int n = t >> 3, sub = t & 7;
        int c = nbase + n;
        if (c < N_NODES) {
            const float* xi = &xs[n * F_IN];
            float a0 = 0.f, a1 = 0.f;
            for (int k = 0; k < F_IN; k++) {
                float xv = xi[k];
                a0 += xv * sW[k * H_DIM + 2 * sub];
                a1 += xv * sW[k * H_DIM + 2 * sub + 1];
            }
            float di = sdinv[n];
            unsigned pk = bf16rne(di * a0) | (bf16rne(di * a1) << 16);
            h1b[(size_t)c * 8 + sub] = pk;        // 32B/node, coalesced
        }
    }
}

// ---------- pass 2: scatter edges directly into exact CSR slots.
// 12.8 MB destination = 1.6 MB/XCD -> L2-resident; lines fill in L2,
// written to HBM once. 1 edge/thread for max TLP over the atomic latency.
__global__ __launch_bounds__(256) void k_scatter(
    const int* __restrict__ row, const int* __restrict__ col,
    const float* __restrict__ w, int* __restrict__ cur,
    unsigned* __restrict__ ebuf4)
{
    int e = blockIdx.x * 256 + threadIdx.x;       // exact fit: 12500*256 = 3.2M
    int r = __builtin_nontemporal_load(&row[e]);
    int c = __builtin_nontemporal_load(&col[e]);
    float wv = __builtin_nontemporal_load(&w[e]);
    int pos = atomicAdd(&cur[c], 1);
    ebuf4[pos] = (bf16rne(wv) << 17) | (unsigned)r;
}

// ---------- layer 1: 16 lanes/node = 2 feature-halves x 8 segment-eighths ----------
__global__ __launch_bounds__(256) void k_agg1(
    const int2* __restrict__ rp, const unsigned* __restrict__ ebuf4,
    const uint4* __restrict__ h1b, const float* __restrict__ dinv,
    const float* __restrict__ b1, const float* __restrict__ W2,
    float* __restrict__ h2s)
{
    __shared__ float sW2[H_DIM * C_DIM];
    __shared__ float sb1[H_DIM];
    int t = threadIdx.x;
    if (t < H_DIM * C_DIM) sW2[t] = W2[t];
    if (t >= 32 && t < 32 + H_DIM) sb1[t - 32] = b1[t - 32];
    __syncthreads();
    int id = blockIdx.x * 256 + t;
    int c = id >> 4;                           // 16 lanes per node
    int sub = id & 15, q = sub & 1, h = sub >> 1;
    if (c >= N_NODES) return;
    int2 seg = rp[c];
    int s = seg.x, n = seg.y;
    int m = (n - h + 7) >> 3;                  // edges for this eighth (stride 8)
    int p0i = s + h;
    float acc[8] = {0.f, 0.f, 0.f, 0.f, 0.f, 0.f, 0.f, 0.f};

#define PROC1(u)                                                    \
    {   float a = EW(u);                                            \
        uint4 g = h1b[(size_t)ER(u) * 2 + q];                       \
        acc[0] += a * BLO(g.x); acc[1] += a * BHI(g.x);             \
        acc[2] += a * BLO(g.y); acc[3] += a * BHI(g.y);             \
        acc[4] += a * BLO(g.z); acc[5] += a * BHI(g.z);             \
        acc[6] += a * BLO(g.w); acc[7] += a * BHI(g.w); }

    int k = 0;
    if (m >= 4) {
        unsigned e0 = __builtin_nontemporal_load(&ebuf4[p0i + 0]);
        unsigned e1 = __builtin_nontemporal_load(&ebuf4[p0i + 8]);
        unsigned e2 = __builtin_nontemporal_load(&ebuf4[p0i + 16]);
        unsigned e3 = __builtin_nontemporal_load(&ebuf4[p0i + 24]);
        for (; k + 8 <= m; k += 4) {
            unsigned f0 = __builtin_nontemporal_load(&ebuf4[p0i + 8 * (k + 4)]);
            unsigned f1 = __builtin_nontemporal_load(&ebuf4[p0i + 8 * (k + 5)]);
            unsigned f2 = __builtin_nontemporal_load(&ebuf4[p0i + 8 * (k + 6)]);
            unsigned f3 = __builtin_nontemporal_load(&ebuf4[p0i + 8 * (k + 7)]);
            PROC1(e0); PROC1(e1); PROC1(e2); PROC1(e3);
            e0 = f0; e1 = f1; e2 = f2; e3 = f3;
        }
        PROC1(e0); PROC1(e1); PROC1(e2); PROC1(e3);
        k += 4;
    }
    for (; k < m; k++) {
        unsigned u = __builtin_nontemporal_load(&ebuf4[p0i + 8 * k]);
        PROC1(u);
    }
#undef PROC1

    // combine the 8 segment-eighths (sub bits 1-3)
#pragma unroll
    for (int j = 0; j < 8; j++) {
        acc[j] += __shfl_xor(acc[j], 2);
        acc[j] += __shfl_xor(acc[j], 4);
        acc[j] += __shfl_xor(acc[j], 8);
    }

    float dc = dinv[c];
    uint4 gc = h1b[(size_t)c * 2 + q];
    float hcv[8] = {BLO(gc.x), BHI(gc.x), BLO(gc.y), BHI(gc.y),
                    BLO(gc.z), BHI(gc.z), BLO(gc.w), BHI(gc.w)};
    int j0 = q << 3;
    float p0 = 0.f, p1 = 0.f;
#pragma unroll
    for (int j = 0; j < 8; j++) {
        float rv = fmaxf(dc * (acc[j] + hcv[j]) + sb1[j0 + j], 0.f);
        p0 += rv * sW2[(j0 + j) * C_DIM + 0];
        p1 += rv * sW2[(j0 + j) * C_DIM + 1];
    }
    // combine the two feature halves (sub bit 0)
    p0 += __shfl_xor(p0, 1);
    p1 += __shfl_xor(p1, 1);
    if (sub == 0) ((float2*)h2s)[c] = make_float2(dc * p0, dc * p1);
}

// ---------- layer 2: 8 lanes/node (segment eighths), shfl reduce,
//            + bias + log_softmax ----------
__global__ __launch_bounds__(256) void k_agg2(
    const int2* __restrict__ rp, const unsigned* __restrict__ ebuf4,
    const float* __restrict__ h2s, const float* __restrict__ dinv,
    const float* __restrict__ b2, float* __restrict__ out)
{
    int id = blockIdx.x * 256 + threadIdx.x;
    int c = id >> 3, sub = id & 7;
    if (c >= N_NODES) return;
    int2 seg = rp[c];
    int s = seg.x, n = seg.y;
    const float2* h22 = (const float2*)h2s;
    int m = (n - sub + 7) >> 3;                // edges for this eighth (stride 8)
    int p0i = s + sub;
    float a0 = 0.f, a1 = 0.f;

#define PROC2(u)                                                    \
    {   float a = EW(u);                                            \
        float2 hv = h22[ER(u)];                                     \
        a0 += a * hv.x;  a1 += a * hv.y; }

    int k = 0;
    if (m >= 4) {
        unsigned e0 = __builtin_nontemporal_load(&ebuf4[p0i + 0]);
        unsigned e1 = __builtin_nontemporal_load(&ebuf4[p0i + 8]);
        unsigned e2 = __builtin_nontemporal_load(&ebuf4[p0i + 16]);
        unsigned e3 = __builtin_nontemporal_load(&ebuf4[p0i + 24]);
        for (; k + 8 <= m; k += 4) {
            unsigned f0 = __builtin_nontemporal_load(&ebuf4[p0i + 8 * (k + 4)]);
            unsigned f1 = __builtin_nontemporal_load(&ebuf4[p0i + 8 * (k + 5)]);
            unsigned f2 = __builtin_nontemporal_load(&ebuf4[p0i + 8 * (k + 6)]);
            unsigned f3 = __builtin_nontemporal_load(&ebuf4[p0i + 8 * (k + 7)]);
            PROC2(e0); PROC2(e1); PROC2(e2); PROC2(e3);
            e0 = f0; e1 = f1; e2 = f2; e3 = f3;
        }
        PROC2(e0); PROC2(e1); PROC2(e2); PROC2(e3);
        k += 4;
    }
    for (; k < m; k++) {
        unsigned u = __builtin_nontemporal_load(&ebuf4[p0i + 8 * k]);
        PROC2(u);
    }
#undef PROC2

    a0 += __shfl_xor(a0, 1); a0 += __shfl_xor(a0, 2); a0 += __shfl_xor(a0, 4);
    a1 += __shfl_xor(a1, 1); a1 += __shfl_xor(a1, 2); a1 += __shfl_xor(a1, 4);
    if (sub == 0) {
        float dc = dinv[c];
        float2 hc = h22[c];
        float l0 = dc * (a0 + hc.x) + b2[0];
        float l1 = dc * (a1 + hc.y) + b2[1];
        float mx = fmaxf(l0, l1);
        float lse = mx + logf(expf(l0 - mx) + expf(l1 - mx));
        ((float2*)out)[c] = make_float2(l0 - lse, l1 - lse);
    }
}

extern "C" void kernel_launch(void* const* d_in, const int* in_sizes, int n_in,
                              void* d_out, int out_size, void* d_ws, size_t ws_size,
                              hipStream_t stream) {
    const float* x  = (const float*)d_in[0];
    const int*   ei = (const int*)d_in[1];     // [2, E]: row then col
    const float* w  = (const float*)d_in[2];
    const float* W1 = (const float*)d_in[3];
    const float* b1 = (const float*)d_in[4];
    const float* W2 = (const float*)d_in[5];
    const float* b2 = (const float*)d_in[6];
    float* out = (float*)d_out;

    const int* row = ei;
    const int* col = ei + N_EDGES;

    // workspace layout (64B-aligned offsets)
    char* ws = (char*)d_ws;
    unsigned long long* acc = (unsigned long long*)(ws + 0);   //   802,816 B (100352 u64)
    int*      tmpbase = (int*)(ws + 802816);     //   401,408 B (100352)
    int*      blockoff= (int*)(ws + 1204224);    //       512 B (128)
    int*      partial = (int*)(ws + 1204736);    //       512 B (128)
    int*      cur     = (int*)(ws + 1205248);    //   400,000 B
    int2*     rp      = (int2*)(ws + 1605248);   //   800,000 B
    float*    dinv    = (float*)(ws + 2405248);  //   400,000 B
    unsigned* h1b     = (unsigned*)(ws + 2805248); // 3,200,000 B (bf16 16/row)
    float*    h2s     = (float*)(ws + 6005248);  //   800,000 B
    unsigned* ebuf4   = (unsigned*)(ws + 6805248); // 12,800,000 B (exact CSR)
    // end: 19,605,248 B

    hipMemsetAsync(acc, 0, 802816, stream);      // node accumulators = 0
    k_hist    <<<3125, 256, 0, stream>>>(col, w, acc);          // E/4 quads
    k_scan1   <<<NSCAN, 1024, 0, stream>>>(acc, tmpbase, partial);
    k_scan2   <<<1, 128, 0, stream>>>(partial, blockoff);
    k_xw1     <<<NXW1, 1024, 0, stream>>>(acc, tmpbase, blockoff, x, W1, rp, cur, dinv, h1b);
    k_scatter <<<12500, 256, 0, stream>>>(row, col, w, cur, ebuf4);
    k_agg1    <<<(16 * N_NODES + 255) / 256, 256, 0, stream>>>(rp, ebuf4, (const uint4*)h1b, dinv, b1, W2, h2s);
    k_agg2    <<<(8 * N_NODES + 255) / 256, 256, 0, stream>>>(rp, ebuf4, h2s, dinv, b2, out);
}

// Round 5
// 527.382 us; speedup vs baseline: 1.0390x; 1.0390x over previous
//
#include <hip/hip_runtime.h>
#include <math.h>

#define N_NODES 100000
#define N_EDGES 3200000
#define F_IN    37
#define H_DIM   16
#define C_DIM   2

#define BUCKET_BITS 7
#define BUCKET_SZ   128
#define NBUCK       782          // ceil(100000/128)
#define CAP         4736         // bucket capacity: mean ~4092 + 10 sigma
#define NPBLK       512          // k_part grid (2 blocks/CU)
#define EB          6250         // edges per part block (512*6250 = 3.2M exactly)
#define EPT_P       7            // ceil(6250/1024)
#define NPAGE       782          // ceil(EB/8) pages for sweep lookup
#define EBUF_SLOTS  (NBUCK * CAP + EB)   // +slack so clamped writes stay in-buffer

__device__ __forceinline__ unsigned bf16rne(float f) {
    unsigned u = __float_as_uint(f);
    return (u + 0x7FFFu + ((u >> 16) & 1u)) >> 16;
}
__device__ __forceinline__ int2 ldnt_i2(const int2* p) {
    long long v = __builtin_nontemporal_load((const long long*)p);
    return *(int2*)&v;
}
#define BLO(u) __uint_as_float((u) << 16)
#define BHI(u) __uint_as_float((u) & 0xFFFF0000u)

// ---------- partition: LDS-staged counting sort per chunk -> linear write-out.
// (R17 win, re-proven by R2's 15x write-amp disaster: lines must be produced
// back-to-back in time by one CU.) Hardened: all theoretically-unbounded
// constructs clamped (unreachable on expected input; fault-proofing only).
__global__ __launch_bounds__(1024) void k_part(
    const int* __restrict__ row, const int* __restrict__ col,
    const float* __restrict__ w, int* __restrict__ gcur, int2* __restrict__ ebuf)
{
    __shared__ int  cnt[NBUCK];
    __shared__ int  base[NBUCK];               // inclusive scan
    __shared__ int  gbase[NBUCK];
    __shared__ int  wscan[16];                 // per-wave scan sums
    __shared__ unsigned short pg2b[NPAGE];     // page -> bucket containing 8p
    __shared__ int2 stage[EB];                 // 50 KB
    int t = threadIdx.x;
    size_t e0 = (size_t)blockIdx.x * EB;
    int bk[EPT_P], rc[EPT_P], lofs[EPT_P];
    float wv[EPT_P];

    if (t < NBUCK) cnt[t] = 0;
    __syncthreads();
#pragma unroll
    for (int k = 0; k < EPT_P; k++) {
        int i = k * 1024 + t;
        if (i < EB) {
            size_t e = e0 + i;
            int r = __builtin_nontemporal_load(&row[e]);
            int c = __builtin_nontemporal_load(&col[e]);
            wv[k] = __builtin_nontemporal_load(&w[e]);
            bk[k] = (c >> BUCKET_BITS) & 1023;         // clamp-mask (c<2^17 anyway)
            if (bk[k] >= NBUCK) bk[k] = NBUCK - 1;     // unreachable guard
            rc[k] = (r & 0x1FFFF) | ((c & (BUCKET_SZ - 1)) << 17);
            lofs[k] = atomicAdd(&cnt[bk[k]], 1);
        } else bk[k] = -1;
    }
    __syncthreads();
    // ---- inclusive scan of cnt[782]: per-wave shfl scan + cross-wave ----
    {
        int lane = t & 63, wid = t >> 6;
        int v = (t < NBUCK) ? cnt[t] : 0;
#pragma unroll
        for (int d = 1; d < 64; d <<= 1) {
            int u = __shfl_up(v, d);
            if (lane >= d) v += u;
        }
        if (lane == 63) wscan[wid] = v;
        __syncthreads();
        if (wid == 0) {
            int u = (lane < 16) ? wscan[lane] : 0;
#pragma unroll
            for (int d = 1; d < 16; d <<= 1) {
                int u2 = __shfl_up(u, d);
                if (lane >= d) u += u2;
            }
            if (lane < 16) wscan[lane] = u;    // inclusive scan of wave sums
        }
        __syncthreads();
        if (t < NBUCK) base[t] = v + ((wid > 0) ? wscan[wid - 1] : 0);
    }
    __syncthreads();
    // scatter into LDS stage, bucket-sorted; build page->bucket table
#pragma unroll
    for (int k = 0; k < EPT_P; k++) {
        if (bk[k] >= 0) {
            int pos = base[bk[k]] - cnt[bk[k]] + lofs[k];
            if (pos >= 0 && pos < EB) stage[pos] =     // unreachable guard
                make_int2(rc[k], __float_as_int(wv[k]));
        }
    }
    if (t < NBUCK) {
        int st = base[t] - cnt[t], en = base[t];
        int p0 = (st + 7) >> 3, p1 = (en - 1) >> 3;
        if (p0 < 0) p0 = 0;
        if (p1 >= NPAGE) p1 = NPAGE - 1;               // unreachable guard
        for (int p = p0; p <= p1; p++)
            pg2b[p] = (unsigned short)t;       // unique containing bucket per page
        gbase[t] = t * CAP + atomicAdd(&gcur[t], cnt[t]);
    }
    __syncthreads();
    // linear sweep write-out (stride-1024: coalesced full-line writes)
    for (int s2 = t; s2 < EB; s2 += 1024) {
        int lo = pg2b[s2 >> 3];
        while (lo < NBUCK - 1 && base[lo] <= s2) lo++; // bounded walk
        int dst = gbase[lo] + (s2 - (base[lo] - cnt[lo]));
        if (dst >= 0 && dst < EBUF_SLOTS)              // unreachable guard
            ebuf[dst] = stage[s2];
    }
}

// ---------- fused: deg via LDS f32 atomics (no sort!) + dinv
//            + h1b = bf16(dinv * (x @ W1)) for this bucket's nodes ----------
__global__ __launch_bounds__(1024) void k_degxw1(
    const int* __restrict__ gcur, const int2* __restrict__ ebuf,
    const float* __restrict__ x, const float* __restrict__ W1,
    float* __restrict__ dinv, unsigned* __restrict__ h1b)
{
    __shared__ float sdeg[BUCKET_SZ];
    __shared__ float sdinv[BUCKET_SZ];
    __shared__ float xs[BUCKET_SZ * F_IN];    // 18.5 KB
    __shared__ float sW[F_IN * H_DIM];        // 2.4 KB
    int t = threadIdx.x, b = blockIdx.x;
    int s = b * CAP;
    int len = gcur[b];
    if (len > CAP) len = CAP;                 // unreachable guard
    int nbase = b << BUCKET_BITS;

    if (t < BUCKET_SZ) sdeg[t] = 0.f;
    for (int idx = t; idx < F_IN * H_DIM; idx += 1024) sW[idx] = W1[idx];
    // stage x while sdeg is zeroed (separate LDS regions, one barrier below)
    {
        const float4* x4 = (const float4*)(x + (size_t)nbase * F_IN);
        const int nv4 = (BUCKET_SZ * F_IN) / 4;   // 1184
        int gf0 = nbase * F_IN;
        for (int idx = t; idx < nv4; idx += 1024) {
            int gf = gf0 + 4 * idx;
            float4 v;
            if (gf + 3 < N_NODES * F_IN) {
                v = x4[idx];
            } else {
                v.x = (gf + 0 < N_NODES * F_IN) ? x[gf + 0] : 0.f;
                v.y = (gf + 1 < N_NODES * F_IN) ? x[gf + 1] : 0.f;
                v.z = (gf + 2 < N_NODES * F_IN) ? x[gf + 2] : 0.f;
                v.w = (gf + 3 < N_NODES * F_IN) ? x[gf + 3] : 0.f;
            }
            ((float4*)xs)[idx] = v;
        }
    }
    __syncthreads();                          // sdeg zeroed before atomics
    for (int i = t; i < len; i += 1024) {
        int2 v = ldnt_i2(&ebuf[s + i]);
        atomicAdd(&sdeg[(v.x >> 17) & (BUCKET_SZ - 1)], __int_as_float(v.y));
    }
    __syncthreads();
    if (t < BUCKET_SZ) {
        float di = rsqrtf(sdeg[t] + 1.0f);    // + self-loop
        sdinv[t] = di;
        int c = nbase + t;
        if (c < N_NODES) dinv[c] = di;
    }
    __syncthreads();
    // 8 threads/node, each computes 2 output cols {2*sub, 2*sub+1}
    {
        int n = t >> 3, sub = t & 7;
        int c = nbase + n;
        if (c < N_NODES) {
            const float* xi = &xs[n * F_IN];
            float a0 = 0.f, a1 = 0.f;
            for (int k = 0; k < F_IN; k++) {
                float xv = xi[k];
                a0 += xv * sW[k * H_DIM + 2 * sub];
                a1 += xv * sW[k * H_DIM + 2 * sub + 1];
            }
            float di = sdinv[n];
            unsigned pk = bf16rne(di * a0) | (bf16rne(di * a1) << 16);
            h1b[(size_t)c * 8 + sub] = pk;    // 32B/node, coalesced
        }
    }
}

// ---------- layer 1: bucket-wise LDS scatter-accumulate.
// 8 lanes/edge: one coalesced 32B h1b gather per edge + 2 ds_add_f32/lane.
// Deletes the CSR segment walk (and the intra-bucket sort) entirely. ----------
__global__ __launch_bounds__(1024) void k_agg1b(
    const int* __restrict__ gcur, const int2* __restrict__ ebuf,
    const unsigned* __restrict__ h1b, const float* __restrict__ dinv,
    const float* __restrict__ b1, const float* __restrict__ W2,
    float* __restrict__ h2s)
{
    __shared__ float acc[BUCKET_SZ * H_DIM];  // 8 KB
    __shared__ float sW2[H_DIM * C_DIM];
    __shared__ float sb1[H_DIM];
    int t = threadIdx.x, b = blockIdx.x;
    int s = b * CAP;
    int len = gcur[b];
    if (len > CAP) len = CAP;                 // unreachable guard
    int nbase = b << BUCKET_BITS;
    if (t < H_DIM * C_DIM) sW2[t] = W2[t];
    if (t >= 64 && t < 64 + H_DIM) sb1[t - 64] = b1[t - 64];
    for (int i = t; i < BUCKET_SZ * H_DIM; i += 1024) acc[i] = 0.f;
    __syncthreads();

    int j = t & 7;                            // feature-pair lane
    for (int e = t >> 3; e < len; e += 128) {
        int2 v = ldnt_i2(&ebuf[s + e]);       // 8 lanes same addr -> broadcast
        float wv = __int_as_float(v.y);
        int r = v.x & 0x1FFFF, cl = (v.x >> 17) & (BUCKET_SZ - 1);
        unsigned g = h1b[(size_t)r * 8 + j];  // 32B coalesced per edge-group
        atomicAdd(&acc[cl * H_DIM + 2 * j],     wv * BLO(g));
        atomicAdd(&acc[cl * H_DIM + 2 * j + 1], wv * BHI(g));
    }
    __syncthreads();

    // epilogue: 8 lanes/node x 128 nodes = 1024 threads exactly
    int n = t >> 3, sub = t & 7;
    int c = nbase + n;
    if (c < N_NODES) {
        float dc = dinv[c];
        unsigned gs = h1b[(size_t)c * 8 + sub];  // self term
        float r0 = fmaxf(dc * (acc[n * H_DIM + 2 * sub]     + BLO(gs)) + sb1[2 * sub],     0.f);
        float r1 = fmaxf(dc * (acc[n * H_DIM + 2 * sub + 1] + BHI(gs)) + sb1[2 * sub + 1], 0.f);
        float p0 = r0 * sW2[(2 * sub) * C_DIM + 0] + r1 * sW2[(2 * sub + 1) * C_DIM + 0];
        float p1 = r0 * sW2[(2 * sub) * C_DIM + 1] + r1 * sW2[(2 * sub + 1) * C_DIM + 1];
        p0 += __shfl_xor(p0, 1); p0 += __shfl_xor(p0, 2); p0 += __shfl_xor(p0, 4);
        p1 += __shfl_xor(p1, 1); p1 += __shfl_xor(p1, 2); p1 += __shfl_xor(p1, 4);
        if (sub == 0) ((float2*)h2s)[c] = make_float2(dc * p0, dc * p1);
    }
}

// ---------- layer 2: bucket-wise LDS scatter-accumulate (2 cols)
//            + bias + log_softmax ----------
__global__ __launch_bounds__(1024) void k_agg2b(
    const int* __restrict__ gcur, const int2* __restrict__ ebuf,
    const float* __restrict__ h2s, const float* __restrict__ dinv,
    const float* __restrict__ b2, float* __restrict__ out)
{
    __shared__ float acc2[BUCKET_SZ * 2];
    int t = threadIdx.x, b = blockIdx.x;
    int s = b * CAP;
    int len = gcur[b];
    if (len > CAP) len = CAP;                 // unreachable guard
    int nbase = b << BUCKET_BITS;
    if (t < BUCKET_SZ * 2) acc2[t] = 0.f;
    __syncthreads();
    const float2* h22 = (const float2*)h2s;
    for (int e = t; e < len; e += 1024) {
        int2 v = ldnt_i2(&ebuf[s + e]);
        float wv = __int_as_float(v.y);
        int r = v.x & 0x1FFFF, cl = (v.x >> 17) & (BUCKET_SZ - 1);
        float2 hv = h22[r];
        atomicAdd(&acc2[cl * 2],     wv * hv.x);
        atomicAdd(&acc2[cl * 2 + 1], wv * hv.y);
    }
    __syncthreads();
    if (t < BUCKET_SZ) {
        int c = nbase + t;
        if (c < N_NODES) {
            float dc = dinv[c];
            float2 hc = h22[c];
            float l0 = dc * (acc2[t * 2]     + hc.x) + b2[0];
            float l1 = dc * (acc2[t * 2 + 1] + hc.y) + b2[1];
            float mx = fmaxf(l0, l1);
            float lse = mx + logf(expf(l0 - mx) + expf(l1 - mx));
            ((float2*)out)[c] = make_float2(l0 - lse, l1 - lse);
        }
    }
}

extern "C" void kernel_launch(void* const* d_in, const int* in_sizes, int n_in,
                              void* d_out, int out_size, void* d_ws, size_t ws_size,
                              hipStream_t stream) {
    const float* x  = (const float*)d_in[0];
    const int*   ei = (const int*)d_in[1];     // [2, E]: row then col
    const float* w  = (const float*)d_in[2];
    const float* W1 = (const float*)d_in[3];
    const float* b1 = (const float*)d_in[4];
    const float* W2 = (const float*)d_in[5];
    const float* b2 = (const float*)d_in[6];
    float* out = (float*)d_out;

    const int* row = ei;
    const int* col = ei + N_EDGES;

    // workspace layout (64B-aligned offsets)
    char* ws = (char*)d_ws;
    int*      gcur = (int*)(ws + 0);             //     3,200 B
    float*    dinv = (float*)(ws + 3200);        //   400,000 B
    unsigned* h1b  = (unsigned*)(ws + 403200);   // 3,200,000 B (bf16 16/row)
    float*    h2s  = (float*)(ws + 3603200);     //   800,000 B
    int2*     ebuf = (int2*)(ws + 4403200);      // 29,678,416 B (EBUF_SLOTS*8)
    // end: 34,081,616 B

    hipMemsetAsync(gcur, 0, 3200, stream);       // bucket counters = 0
    k_part    <<<NPBLK, 1024, 0, stream>>>(row, col, w, gcur, ebuf);
    k_degxw1  <<<NBUCK, 1024, 0, stream>>>(gcur, ebuf, x, W1, dinv, h1b);
    k_agg1b   <<<NBUCK, 1024, 0, stream>>>(gcur, ebuf, h1b, dinv, b1, W2, h2s);
    k_agg2b   <<<NBUCK, 1024, 0, stream>>>(gcur, ebuf, h2s, dinv, b2, out);
}

// Round 7
// 190.983 us; speedup vs baseline: 2.8690x; 2.7614x over previous
//
#include <hip/hip_runtime.h>
#include <math.h>

#define N_NODES 100000
#define N_EDGES 3200000
#define F_IN    37
#define H_DIM   16
#define C_DIM   2

#define BUCKET_BITS 7
#define BUCKET_SZ   128
#define NBUCK       782          // ceil(100000/128)
#define CAP         4736         // bucket capacity: mean ~4092 + 10 sigma
#define NPBLK       512          // k_part grid (2 blocks/CU)
#define EB          6250         // edges per part block (512*6250 = 3.2M exactly)
#define EPT_P       7            // ceil(6250/1024)
#define EPT_S       5            // ceil(CAP/1024)
#define NPAGE       782          // ceil(EB/8) pages for sweep lookup
#define EBUF_SLOTS  (NBUCK * CAP + EB)   // +slack so clamped writes stay in-buffer

__device__ __forceinline__ unsigned bf16rne(float f) {
    unsigned u = __float_as_uint(f);
    return (u + 0x7FFFu + ((u >> 16) & 1u)) >> 16;
}
__device__ __forceinline__ int2 ldnt_i2(const int2* p) {
    long long v = __builtin_nontemporal_load((const long long*)p);
    return *(int2*)&v;
}
#define BLO(u) __uint_as_float((u) << 16)
#define BHI(u) __uint_as_float((u) & 0xFFFF0000u)
// compact edge decode: u = (w_bf16 << 17) | row   (w in [0,1) => sign bit 0)
#define EW(u)  __uint_as_float(((u) >> 17) << 16)
#define ER(u)  ((u) & 0x1FFFFu)

// ---------- partition: LDS-staged counting sort per chunk -> linear write-out.
// (Proven at 191us R1 + hardening guards proven in R5's passing run.)
__global__ __launch_bounds__(1024) void k_part(
    const int* __restrict__ row, const int* __restrict__ col,
    const float* __restrict__ w, int* __restrict__ gcur, int2* __restrict__ ebuf)
{
    __shared__ int  cnt[NBUCK];
    __shared__ int  base[NBUCK];               // inclusive scan
    __shared__ int  gbase[NBUCK];
    __shared__ int  wscan[16];                 // per-wave scan sums
    __shared__ unsigned short pg2b[NPAGE];     // page -> bucket containing 8p
    __shared__ int2 stage[EB];                 // 50 KB
    int t = threadIdx.x;
    size_t e0 = (size_t)blockIdx.x * EB;
    int bk[EPT_P], rc[EPT_P], lofs[EPT_P];
    float wv[EPT_P];

    if (t < NBUCK) cnt[t] = 0;
    __syncthreads();
#pragma unroll
    for (int k = 0; k < EPT_P; k++) {
        int i = k * 1024 + t;
        if (i < EB) {
            size_t e = e0 + i;
            int r = __builtin_nontemporal_load(&row[e]);
            int c = __builtin_nontemporal_load(&col[e]);
            wv[k] = __builtin_nontemporal_load(&w[e]);
            bk[k] = (c >> BUCKET_BITS) & 1023;         // clamp-mask (c<2^17 anyway)
            if (bk[k] >= NBUCK) bk[k] = NBUCK - 1;     // unreachable guard
            rc[k] = (r & 0x1FFFF) | ((c & (BUCKET_SZ - 1)) << 17);
            lofs[k] = atomicAdd(&cnt[bk[k]], 1);
        } else bk[k] = -1;
    }
    __syncthreads();
    // ---- inclusive scan of cnt[782]: per-wave shfl scan + cross-wave ----
    {
        int lane = t & 63, wid = t >> 6;
        int v = (t < NBUCK) ? cnt[t] : 0;
#pragma unroll
        for (int d = 1; d < 64; d <<= 1) {
            int u = __shfl_up(v, d);
            if (lane >= d) v += u;
        }
        if (lane == 63) wscan[wid] = v;
        __syncthreads();
        if (wid == 0) {
            int u = (lane < 16) ? wscan[lane] : 0;
#pragma unroll
            for (int d = 1; d < 16; d <<= 1) {
                int u2 = __shfl_up(u, d);
                if (lane >= d) u += u2;
            }
            if (lane < 16) wscan[lane] = u;    // inclusive scan of wave sums
        }
        __syncthreads();
        if (t < NBUCK) base[t] = v + ((wid > 0) ? wscan[wid - 1] : 0);
    }
    __syncthreads();
    // scatter into LDS stage, bucket-sorted; build page->bucket table
#pragma unroll
    for (int k = 0; k < EPT_P; k++) {
        if (bk[k] >= 0) {
            int pos = base[bk[k]] - cnt[bk[k]] + lofs[k];
            if (pos >= 0 && pos < EB) stage[pos] =     // unreachable guard
                make_int2(rc[k], __float_as_int(wv[k]));
        }
    }
    if (t < NBUCK) {
        int st = base[t] - cnt[t], en = base[t];
        int p0 = (st + 7) >> 3, p1 = (en - 1) >> 3;
        if (p0 < 0) p0 = 0;
        if (p1 >= NPAGE) p1 = NPAGE - 1;               // unreachable guard
        for (int p = p0; p <= p1; p++)
            pg2b[p] = (unsigned short)t;       // unique containing bucket per page
        gbase[t] = t * CAP + atomicAdd(&gcur[t], cnt[t]);
    }
    __syncthreads();
    // linear sweep write-out (stride-1024: coalesced full-line writes)
    for (int s2 = t; s2 < EB; s2 += 1024) {
        int lo = pg2b[s2 >> 3];
        while (lo < NBUCK - 1 && base[lo] <= s2) lo++; // bounded walk
        int dst = gbase[lo] + (s2 - (base[lo] - cnt[lo]));
        if (dst >= 0 && dst < EBUF_SLOTS)              // unreachable guard
            ebuf[dst] = stage[s2];
    }
}

// ---------- fused: per-bucket LDS counting sort -> compact 4B edges + CSR
//            + dinv + h1b = bf16(dinv * (x @ W1)).  (R1-proven, + guards.)
// The sort is what converts aggregation into VGPR accumulation — R5 measured
// the no-sort LDS-atomic alternative at the 4 cyc/lane-atomic ceiling (338us).
__global__ __launch_bounds__(1024) void k_sortxw1(
    const int* __restrict__ gcur, const int2* __restrict__ ebuf,
    const float* __restrict__ x, const float* __restrict__ W1,
    unsigned* __restrict__ ebuf4, int2* __restrict__ rp,
    float* __restrict__ dinv, unsigned* __restrict__ h1b)
{
    __shared__ int2  stage[CAP];              // 37.9 KB (reused as xs below)
    __shared__ int   cnt[BUCKET_SZ];
    __shared__ int   base[BUCKET_SZ];
    __shared__ float sdinv[BUCKET_SZ];
    __shared__ int   wscan[16];
    __shared__ float sW[F_IN * H_DIM];        // 2.4 KB
    float* xs = (float*)stage;                // aliased reuse: 128*37 floats

    int t = threadIdx.x, b = blockIdx.x;
    int s = b * CAP;
    int len = gcur[b];
    if (len > CAP) len = CAP;                 // unreachable guard
    int nbase = b << BUCKET_BITS;
    if (t < BUCKET_SZ) cnt[t] = 0;
    __syncthreads();

    // ---- load + count ----
    int2 ed[EPT_S]; int cl[EPT_S], lofs[EPT_S];
#pragma unroll
    for (int k = 0; k < EPT_S; k++) {
        int i = k * 1024 + t;
        if (i < len) {
            int2 v = ldnt_i2(&ebuf[s + i]);
            ed[k] = v;
            cl[k] = (v.x >> 17) & (BUCKET_SZ - 1);
            lofs[k] = atomicAdd(&cnt[cl[k]], 1);
        } else cl[k] = -1;
    }
    __syncthreads();
    // ---- inclusive scan of cnt[128]: per-wave shfl scan + cross-wave ----
    {
        int lane = t & 63, wid = t >> 6;
        int v = (t < BUCKET_SZ) ? cnt[t] : 0;
#pragma unroll
        for (int d = 1; d < 64; d <<= 1) {
            int u = __shfl_up(v, d);
            if (lane >= d) v += u;
        }
        if (lane == 63) wscan[wid] = v;
        __syncthreads();
        if (wid == 0) {
            int u = (lane < 16) ? wscan[lane] : 0;
#pragma unroll
            for (int d = 1; d < 16; d <<= 1) {
                int u2 = __shfl_up(u, d);
                if (lane >= d) u += u2;
            }
            if (lane < 16) wscan[lane] = u;
        }
        __syncthreads();
        if (t < BUCKET_SZ) base[t] = v + ((wid > 0) ? wscan[wid - 1] : 0);
    }
    __syncthreads();
    // ---- scatter into LDS stage in node-sorted order ----
#pragma unroll
    for (int k = 0; k < EPT_S; k++) {
        if (cl[k] >= 0) {
            int pos = base[cl[k]] - cnt[cl[k]] + lofs[k];
            if (pos >= 0 && pos < CAP) stage[pos] = ed[k];   // unreachable guard
        }
    }
    __syncthreads();
    // ---- compact 4B write-back (NT, coalesced => full-line writes) ----
    for (int i = t; i < len; i += 1024) {
        int2 v = stage[i];
        unsigned wb = bf16rne(__int_as_float(v.y));
        __builtin_nontemporal_store((wb << 17) | (unsigned)(v.x & 0x1FFFF),
                                    &ebuf4[s + i]);
    }
    // ---- degree -> dinv: 8 threads/node strided + shfl reduce ----
    {
        int n = t >> 3, l = t & 7;
        int st = base[n] - cnt[n], cn = cnt[n];
        float sum = 0.f;
        for (int i = l; i < cn; i += 8) sum += __int_as_float(stage[st + i].y);
        sum += __shfl_xor(sum, 1);
        sum += __shfl_xor(sum, 2);
        sum += __shfl_xor(sum, 4);
        if (l == 0) {
            float di = rsqrtf(sum + 1.0f);    // + self-loop
            sdinv[n] = di;
            int c = nbase + n;
            if (c < N_NODES) {
                rp[c] = make_int2(s + st, cn);
                dinv[c] = di;
            }
        }
    }
    __syncthreads();                          // stage reads done; xs overwrite ok

    // ---- fused xw1 for this bucket's 128 nodes ----
    for (int idx = t; idx < F_IN * H_DIM; idx += 1024) sW[idx] = W1[idx];
    {
        const float4* x4 = (const float4*)(x + (size_t)nbase * F_IN);
        const int nv4 = (BUCKET_SZ * F_IN) / 4;   // 1184
        int gf0 = nbase * F_IN;
        for (int idx = t; idx < nv4; idx += 1024) {
            int gf = gf0 + 4 * idx;
            float4 v;
            if (gf + 3 < N_NODES * F_IN) {
                v = x4[idx];
            } else {
                v.x = (gf + 0 < N_NODES * F_IN) ? x[gf + 0] : 0.f;
                v.y = (gf + 1 < N_NODES * F_IN) ? x[gf + 1] : 0.f;
                v.z = (gf + 2 < N_NODES * F_IN) ? x[gf + 2] : 0.f;
                v.w = (gf + 3 < N_NODES * F_IN) ? x[gf + 3] : 0.f;
            }
            ((float4*)xs)[idx] = v;
        }
    }
    __syncthreads();
    // 8 threads/node, each computes 2 output cols {2*sub, 2*sub+1}
    {
        int n = t >> 3, sub = t & 7;
        int c = nbase + n;
        if (c < N_NODES) {
            const float* xi = &xs[n * F_IN];
            float a0 = 0.f, a1 = 0.f;
            for (int k = 0; k < F_IN; k++) {
                float xv = xi[k];
                a0 += xv * sW[k * H_DIM + 2 * sub];
                a1 += xv * sW[k * H_DIM + 2 * sub + 1];
            }
            float di = sdinv[n];
            unsigned pk = bf16rne(di * a0) | (bf16rne(di * a1) << 16);
            h1b[(size_t)c * 8 + sub] = pk;    // 32B/node, coalesced
        }
    }
}

// ---------- layer 1: 8 lanes/node (segment eighths). Each lane loads the
// edge word ONCE and gathers the full 32B h1b row (2x16B) -> 3 VMEM
// requests/edge vs R1's 4. Per-feature sum order bit-identical to R1
// (same stride-8 eighths, same xor reduction tree). ----------
__global__ __launch_bounds__(256) void k_agg1(
    const int2* __restrict__ rp, const unsigned* __restrict__ ebuf4,
    const uint4* __restrict__ h1b, const float* __restrict__ dinv,
    const float* __restrict__ b1, const float* __restrict__ W2,
    float* __restrict__ h2s)
{
    __shared__ float sW2[H_DIM * C_DIM];
    __shared__ float sb1[H_DIM];
    int t = threadIdx.x;
    if (t < H_DIM * C_DIM) sW2[t] = W2[t];
    if (t >= 32 && t < 32 + H_DIM) sb1[t - 32] = b1[t - 32];
    __syncthreads();
    int id = blockIdx.x * 256 + t;
    int c = id >> 3;                           // 8 lanes per node
    int sub = id & 7;
    if (c >= N_NODES) return;
    int2 seg = rp[c];
    int s = seg.x, n = seg.y;
    int m = (n - sub + 7) >> 3;                // edges for this eighth (stride 8)
    int p0i = s + sub;
    float acc[16];
#pragma unroll
    for (int j = 0; j < 16; j++) acc[j] = 0.f;

#define PROC1(u)                                                    \
    {   float a = EW(u);                                            \
        size_t rr = (size_t)ER(u) * 2;                              \
        uint4 g0 = h1b[rr];                                         \
        uint4 g1 = h1b[rr + 1];                                     \
        acc[0]  += a * BLO(g0.x); acc[1]  += a * BHI(g0.x);         \
        acc[2]  += a * BLO(g0.y); acc[3]  += a * BHI(g0.y);         \
        acc[4]  += a * BLO(g0.z); acc[5]  += a * BHI(g0.z);         \
        acc[6]  += a * BLO(g0.w); acc[7]  += a * BHI(g0.w);         \
        acc[8]  += a * BLO(g1.x); acc[9]  += a * BHI(g1.x);         \
        acc[10] += a * BLO(g1.y); acc[11] += a * BHI(g1.y);         \
        acc[12] += a * BLO(g1.z); acc[13] += a * BHI(g1.z);         \
        acc[14] += a * BLO(g1.w); acc[15] += a * BHI(g1.w); }

    int k = 0;
    if (m >= 4) {
        unsigned e0 = __builtin_nontemporal_load(&ebuf4[p0i + 0]);
        unsigned e1 = __builtin_nontemporal_load(&ebuf4[p0i + 8]);
        unsigned e2 = __builtin_nontemporal_load(&ebuf4[p0i + 16]);
        unsigned e3 = __builtin_nontemporal_load(&ebuf4[p0i + 24]);
        for (; k + 8 <= m; k += 4) {
            unsigned f0 = __builtin_nontemporal_load(&ebuf4[p0i + 8 * (k + 4)]);
            unsigned f1 = __builtin_nontemporal_load(&ebuf4[p0i + 8 * (k + 5)]);
            unsigned f2 = __builtin_nontemporal_load(&ebuf4[p0i + 8 * (k + 6)]);
            unsigned f3 = __builtin_nontemporal_load(&ebuf4[p0i + 8 * (k + 7)]);
            PROC1(e0); PROC1(e1); PROC1(e2); PROC1(e3);
            e0 = f0; e1 = f1; e2 = f2; e3 = f3;
        }
        PROC1(e0); PROC1(e1); PROC1(e2); PROC1(e3);
        k += 4;
    }
    for (; k < m; k++) {
        unsigned u = __builtin_nontemporal_load(&ebuf4[p0i + 8 * k]);
        PROC1(u);
    }
#undef PROC1

    // combine the 8 segment-eighths (same tree shape as R1: pairs first)
#pragma unroll
    for (int j = 0; j < 16; j++) {
        acc[j] += __shfl_xor(acc[j], 1);
        acc[j] += __shfl_xor(acc[j], 2);
        acc[j] += __shfl_xor(acc[j], 4);
    }

    // epilogue: each lane finishes 2 features {2*sub, 2*sub+1}
    float dc = dinv[c];
    const unsigned* h1w = (const unsigned*)h1b;
    unsigned gs = h1w[(size_t)c * 8 + sub];    // self term, 2 bf16 features
    float r0 = fmaxf(dc * (acc[2 * sub]     + BLO(gs)) + sb1[2 * sub],     0.f);
    float r1 = fmaxf(dc * (acc[2 * sub + 1] + BHI(gs)) + sb1[2 * sub + 1], 0.f);
    float p0 = r0 * sW2[(2 * sub) * C_DIM + 0] + r1 * sW2[(2 * sub + 1) * C_DIM + 0];
    float p1 = r0 * sW2[(2 * sub) * C_DIM + 1] + r1 * sW2[(2 * sub + 1) * C_DIM + 1];
    p0 += __shfl_xor(p0, 1); p0 += __shfl_xor(p0, 2); p0 += __shfl_xor(p0, 4);
    p1 += __shfl_xor(p1, 1); p1 += __shfl_xor(p1, 2); p1 += __shfl_xor(p1, 4);
    if (sub == 0) ((float2*)h2s)[c] = make_float2(dc * p0, dc * p1);
}

// ---------- layer 2: 8 lanes/node (segment eighths), shfl reduce,
//            + bias + log_softmax (R1-verbatim, proven) ----------
__global__ __launch_bounds__(256) void k_agg2(
    const int2* __restrict__ rp, const unsigned* __restrict__ ebuf4,
    const float* __restrict__ h2s, const float* __restrict__ dinv,
    const float* __restrict__ b2, float* __restrict__ out)
{
    int id = blockIdx.x * 256 + threadIdx.x;
    int c = id >> 3, sub = id & 7;
    if (c >= N_NODES) return;
    int2 seg = rp[c];
    int s = seg.x, n = seg.y;
    const float2* h22 = (const float2*)h2s;
    int m = (n - sub + 7) >> 3;                // edges for this eighth (stride 8)
    int p0i = s + sub;
    float a0 = 0.f, a1 = 0.f;

#define PROC2(u)                                                    \
    {   float a = EW(u);                                            \
        float2 hv = h22[ER(u)];                                     \
        a0 += a * hv.x;  a1 += a * hv.y; }

    int k = 0;
    if (m >= 4) {
        unsigned e0 = __builtin_nontemporal_load(&ebuf4[p0i + 0]);
        unsigned e1 = __builtin_nontemporal_load(&ebuf4[p0i + 8]);
        unsigned e2 = __builtin_nontemporal_load(&ebuf4[p0i + 16]);
        unsigned e3 = __builtin_nontemporal_load(&ebuf4[p0i + 24]);
        for (; k + 8 <= m; k += 4) {
            unsigned f0 = __builtin_nontemporal_load(&ebuf4[p0i + 8 * (k + 4)]);
            unsigned f1 = __builtin_nontemporal_load(&ebuf4[p0i + 8 * (k + 5)]);
            unsigned f2 = __builtin_nontemporal_load(&ebuf4[p0i + 8 * (k + 6)]);
            unsigned f3 = __builtin_nontemporal_load(&ebuf4[p0i + 8 * (k + 7)]);
            PROC2(e0); PROC2(e1); PROC2(e2); PROC2(e3);
            e0 = f0; e1 = f1; e2 = f2; e3 = f3;
        }
        PROC2(e0); PROC2(e1); PROC2(e2); PROC2(e3);
        k += 4;
    }
    for (; k < m; k++) {
        unsigned u = __builtin_nontemporal_load(&ebuf4[p0i + 8 * k]);
        PROC2(u);
    }
#undef PROC2

    a0 += __shfl_xor(a0, 1); a0 += __shfl_xor(a0, 2); a0 += __shfl_xor(a0, 4);
    a1 += __shfl_xor(a1, 1); a1 += __shfl_xor(a1, 2); a1 += __shfl_xor(a1, 4);
    if (sub == 0) {
        float dc = dinv[c];
        float2 hc = h22[c];
        float l0 = dc * (a0 + hc.x) + b2[0];
        float l1 = dc * (a1 + hc.y) + b2[1];
        float mx = fmaxf(l0, l1);
        float lse = mx + logf(expf(l0 - mx) + expf(l1 - mx));
        ((float2*)out)[c] = make_float2(l0 - lse, l1 - lse);
    }
}

extern "C" void kernel_launch(void* const* d_in, const int* in_sizes, int n_in,
                              void* d_out, int out_size, void* d_ws, size_t ws_size,
                              hipStream_t stream) {
    const float* x  = (const float*)d_in[0];
    const int*   ei = (const int*)d_in[1];     // [2, E]: row then col
    const float* w  = (const float*)d_in[2];
    const float* W1 = (const float*)d_in[3];
    const float* b1 = (const float*)d_in[4];
    const float* W2 = (const float*)d_in[5];
    const float* b2 = (const float*)d_in[6];
    float* out = (float*)d_out;

    const int* row = ei;
    const int* col = ei + N_EDGES;

    // workspace layout (64B-aligned offsets)
    char* ws = (char*)d_ws;
    int*      gcur  = (int*)(ws + 0);            //     3,200 B
    int2*     rp    = (int2*)(ws + 3200);        //   800,000 B
    float*    dinv  = (float*)(ws + 803200);     //   400,000 B
    unsigned* h1b   = (unsigned*)(ws + 1203200); // 3,200,000 B (bf16 16/row)
    float*    h2s   = (float*)(ws + 4403200);    //   800,000 B
    unsigned* ebuf4 = (unsigned*)(ws + 5203200); //14,814,208 B (782*4736*4)
    int2*     ebuf  = (int2*)(ws + 20017408);    //29,678,416 B (EBUF_SLOTS*8)
    // end: 49,695,824 B

    hipMemsetAsync(gcur, 0, 3200, stream);       // bucket counters = 0
    k_part    <<<NPBLK, 1024, 0, stream>>>(row, col, w, gcur, ebuf);
    k_sortxw1 <<<NBUCK, 1024, 0, stream>>>(gcur, ebuf, x, W1, ebuf4, rp, dinv, h1b);
    k_agg1    <<<(8 * N_NODES + 255) / 256, 256, 0, stream>>>(rp, ebuf4, (const uint4*)h1b, dinv, b1, W2, h2s);
    k_agg2    <<<(8 * N_NODES + 255) / 256, 256, 0, stream>>>(rp, ebuf4, h2s, dinv, b2, out);
}